// Round 2
// baseline (781.596 us; speedup 1.0000x reference)
//
#include <hip/hip_runtime.h>

// Problem constants (fixed by the reference):
//   B=4, NV=100000, F=200000, D=64
// verts: [B, NV, 64] f32, faces: [B, F, 3] i32, out: [B, NV, 64] f32
#define BB   4
#define NVV  100000
#define FFC  200000
#define DD   64

// One wave (64 lanes) per face. Lane d owns dimension d.
// Per face (a,b,c): nbr[a]+=v[b]+v[c]; nbr[b]+=v[a]+v[c]; nbr[c]+=v[a]+v[b];
// deg[a]+=2, deg[b]+=2, deg[c]+=2 (multiplicity preserved for degenerate faces).
__global__ __launch_bounds__(256) void ul_scatter(
    const float* __restrict__ v, const int* __restrict__ faces,
    float* __restrict__ nbr, float* __restrict__ deg, int totalFaces)
{
    int gid  = blockIdx.x * blockDim.x + threadIdx.x;
    int wid  = gid >> 6;        // face id
    int lane = gid & 63;        // dim id
    if (wid >= totalFaces) return;

    int b   = wid / FFC;        // batch
    int off = b * NVV;          // vertex offset into flattened [B*NV]
    const int* fp = faces + (size_t)wid * 3;
    int ia = fp[0] + off;
    int ib = fp[1] + off;
    int ic = fp[2] + off;

    float va = v[(size_t)ia * DD + lane];
    float vb = v[(size_t)ib * DD + lane];
    float vc = v[(size_t)ic * DD + lane];

    atomicAdd(&nbr[(size_t)ia * DD + lane], vb + vc);
    atomicAdd(&nbr[(size_t)ib * DD + lane], va + vc);
    atomicAdd(&nbr[(size_t)ic * DD + lane], va + vb);

    if (lane < 3) {
        int t = (lane == 0) ? ia : ((lane == 1) ? ib : ic);
        atomicAdd(&deg[t], 2.0f);
    }
}

// x = (deg*v - nbr) / (deg + 1e-12), elementwise, float4-vectorized.
// nbr lives in d_out; result written in-place.
__global__ __launch_bounds__(256) void ul_finalize(
    const float4* __restrict__ v4, const float* __restrict__ deg,
    float4* __restrict__ out4, int n4)
{
    int i = blockIdx.x * blockDim.x + threadIdx.x;
    if (i >= n4) return;
    float d = deg[i >> 4];            // 16 float4 per 64-dim vertex row
    float4 vv = v4[i];
    float4 nb = out4[i];
    float inv = 1.0f / (d + 1e-12f);
    float4 r;
    r.x = (d * vv.x - nb.x) * inv;
    r.y = (d * vv.y - nb.y) * inv;
    r.z = (d * vv.z - nb.z) * inv;
    r.w = (d * vv.w - nb.w) * inv;
    out4[i] = r;
}

extern "C" void kernel_launch(void* const* d_in, const int* in_sizes, int n_in,
                              void* d_out, int out_size, void* d_ws, size_t ws_size,
                              hipStream_t stream)
{
    const float* verts = (const float*)d_in[0];
    const int*   faces = (const int*)d_in[1];
    float*       out   = (float*)d_out;       // doubles as nbr accumulator
    float*       deg   = (float*)d_ws;        // B*NV floats = 1.6 MB

    const int totalFaces = BB * FFC;          // 800,000
    const size_t outBytes = (size_t)out_size * sizeof(float);
    const size_t degBytes = (size_t)BB * NVV * sizeof(float);

    // d_out / d_ws are poisoned to 0xAA before every timed launch — zero them.
    hipMemsetAsync(d_out, 0, outBytes, stream);
    hipMemsetAsync(d_ws,  0, degBytes, stream);

    // Scatter: one wave per face -> 800k waves, 4 waves per 256-thread block.
    {
        long long threads = (long long)totalFaces * 64;
        int blocks = (int)((threads + 255) / 256);
        ul_scatter<<<blocks, 256, 0, stream>>>(verts, faces, out, deg, totalFaces);
    }

    // Finalize: (deg*v - nbr)/(deg+eps), in-place over d_out.
    {
        int n4 = out_size / 4;                // 6.4M float4
        int blocks = (n4 + 255) / 256;
        ul_finalize<<<blocks, 256, 0, stream>>>(
            (const float4*)verts, deg, (float4*)out, n4);
    }
}